// Round 1
// baseline (929.152 us; speedup 1.0000x reference)
//
#include <hip/hip_runtime.h>
#include <cstdint>
#include <cstddef>

// ---------------------------------------------------------------------------
// WindowAttention: B=1024 windows, N=216 tokens, H=6 heads, D=32, C=192.
// Pipeline: K0 prep (weights->bf16, bias expand) -> K1 fused qkv+attention per
// window (bf16 MFMA, no-max softmax, deferred rowsum) -> K2 proj GEMM in-place
// on d_out. Workspace use: 1.42 MB only. attn intermediate lives as bf16 in
// each window's own d_out region (block-local in-place in K2 => race-free).
// ---------------------------------------------------------------------------

typedef __attribute__((ext_vector_type(8))) short short8;   // 8 x bf16 frag
typedef __attribute__((ext_vector_type(4))) float f32x4;    // MFMA C/D

#define SCALE_F 0.17677669529663687f  /* 32^-0.5 */

__device__ __forceinline__ unsigned short f2bf(float f) {
  union { float f; unsigned u; } v; v.f = f;
  return (unsigned short)((v.u + 0x7fffu + ((v.u >> 16) & 1u)) >> 16);  // RNE
}

__device__ __forceinline__ f32x4 mfma16(short8 a, short8 b, f32x4 c) {
  return __builtin_amdgcn_mfma_f32_16x16x32_bf16(a, b, c, 0, 0, 0);
}

// ---------------------------------------------------------------------------
// K0: qkv_w[576,192]->bf16, proj_w[192,192]->bf16, bias[h][n][m] fp32 expand.
// ---------------------------------------------------------------------------
__global__ void prep_kernel(const float* __restrict__ qkv_w,
                            const float* __restrict__ proj_w,
                            const float* __restrict__ bias_table,
                            unsigned short* __restrict__ wb,
                            unsigned short* __restrict__ pwb,
                            float* __restrict__ biasg) {
  const int tid = blockIdx.x * blockDim.x + threadIdx.x;
  const int stride = gridDim.x * blockDim.x;
  for (int i = tid; i < 576 * 192; i += stride) wb[i] = f2bf(qkv_w[i]);
  for (int i = tid; i < 192 * 192; i += stride) pwb[i] = f2bf(proj_w[i]);
  for (int i = tid; i < 6 * 216 * 216; i += stride) {
    const int h = i / 46656, rem = i % 46656;
    const int n = rem / 216, m = rem % 216;
    const int di = n / 36 - m / 36;
    const int dj = (n / 6) % 6 - (m / 6) % 6;
    const int dk = n % 6 - m % 6;
    const int idx = (di + 5) * 17 + (dj + 5) * 11 + (dk + 5);  // faithful REL_INDEX
    biasg[i] = bias_table[idx * 6 + h];
  }
}

// ---------------------------------------------------------------------------
// K1: per-window fused qkv + attention.
// LDS (dynamic, 157568 B):
//   xs  [216][200] bf16 @0       (x, padded stride: 100 dw -> 2-way banks, free)
//   qs  [224][40]  bf16 @86400   (q rows; rows 216..223 zeroed)
//   ks  [224][40]  bf16 @104320
//   vT  [32][232]  bf16 @122240  (v transposed; cols 216..223 zeroed)
//   pch [16][16][40] bf16 @137088 (per-wave P chunk for C->A layout transform)
// ---------------------------------------------------------------------------
__global__ __launch_bounds__(1024, 4)
void attn_kernel(const float* __restrict__ x, const unsigned short* __restrict__ wb,
                 const float* __restrict__ biasg, float* __restrict__ outbuf) {
  extern __shared__ char smem[];
  unsigned short* xs  = (unsigned short*)(smem);
  unsigned short* qs  = (unsigned short*)(smem + 86400);
  unsigned short* ks  = (unsigned short*)(smem + 104320);
  unsigned short* vT  = (unsigned short*)(smem + 122240);
  unsigned short* pch = (unsigned short*)(smem + 137088);

  const int b = blockIdx.x;
  const int tid = threadIdx.x;
  const int wave = tid >> 6;
  const int lane = tid & 63;
  const int quad = lane >> 4;
  const int lcol = lane & 15;

  // ---- stage x (fp32 -> bf16), zero pads ----
  {
    const float4* xg4 = (const float4*)(x + (size_t)b * 41472);
    for (int i = tid; i < 216 * 48; i += 1024) {
      const int row = i / 48, c4 = i % 48;
      const float4 v = xg4[row * 48 + c4];
      union { unsigned short s[4]; unsigned long long u; } pk;
      pk.s[0] = f2bf(v.x); pk.s[1] = f2bf(v.y);
      pk.s[2] = f2bf(v.z); pk.s[3] = f2bf(v.w);
      *(unsigned long long*)(xs + row * 200 + c4 * 4) = pk.u;
    }
    for (int i = tid; i < 8 * 40; i += 1024) { qs[216 * 40 + i] = 0; ks[216 * 40 + i] = 0; }
    for (int i = tid; i < 32 * 8; i += 1024) vT[(i >> 3) * 232 + 216 + (i & 7)] = 0;
  }
  __syncthreads();

  unsigned short* attnb = (unsigned short*)(outbuf + (size_t)b * 41472);  // bf16 scratch in own region

  for (int h = 0; h < 6; ++h) {
    // ---------- Phase 1: q,k,v = x @ W_h^T  (M=224pad, N=96, K=192) ----------
    // unit = (mt-pair, nt-triple): 14 units over 16 waves; A-frags shared by 3 nt.
    for (int u = wave; u < 14; u += 16) {
      const int mtp = u >> 1;   // 0..6
      const int nh  = u & 1;    // nt base = nh*3
      f32x4 acc[2][3] = {};
#pragma unroll
      for (int kk = 0; kk < 6; ++kk) {
        const short8 a0 = *(const short8*)(xs + (mtp * 32      + lcol) * 200 + kk * 32 + quad * 8);
        const short8 a1 = *(const short8*)(xs + (mtp * 32 + 16 + lcol) * 200 + kk * 32 + quad * 8);
#pragma unroll
        for (int j = 0; j < 3; ++j) {
          const int nt = nh * 3 + j;                         // 0,1=q 2,3=k 4,5=v
          const int fbase = (nt >> 1) * 192 + h * 32 + (nt & 1) * 16;
          const short8 bf = *(const short8*)(wb + (fbase + lcol) * 192 + kk * 32 + quad * 8);
          acc[0][j] = mfma16(a0, bf, acc[0][j]);
          acc[1][j] = mfma16(a1, bf, acc[1][j]);
        }
      }
#pragma unroll
      for (int mi = 0; mi < 2; ++mi) {
        const int nbase = (mtp * 2 + mi) * 16 + quad * 4;    // C row = quad*4+reg
#pragma unroll
        for (int j = 0; j < 3; ++j) {
          const int nt = nh * 3 + j;
#pragma unroll
          for (int r = 0; r < 4; ++r) {
            const int n = nbase + r;
            if (n < 216) {
              const unsigned short val = f2bf(acc[mi][j][r]);
              if (nt < 2)      qs[n * 40 + (nt & 1) * 16 + lcol] = val;
              else if (nt < 4) ks[n * 40 + (nt & 1) * 16 + lcol] = val;
              else             vT[((nt & 1) * 16 + lcol) * 232 + n] = val;  // transposed
            }
          }
        }
      }
    }
    __syncthreads();

    // ---------- Phase 2: S=qk^T*scale+bias, exp (no max needed: |logit|<0.6),
    //            chunked P@V with deferred 1/rowsum ----------
    if (wave < 14) {
      const int s = wave;                       // 16-row strip
      unsigned short* pw_ = pch + wave * 640;   // [16][40]
      const short8 qa = *(const short8*)(qs + (s * 16 + lcol) * 40 + quad * 8);  // K=32 in one frag
      f32x4 o0 = {}, o1 = {}, rsum = {};
      for (int mt2 = 0; mt2 < 7; ++mt2) {       // 32-col chunks
        const short8 kb0 = *(const short8*)(ks + (mt2 * 32      + lcol) * 40 + quad * 8);
        const short8 kb1 = *(const short8*)(ks + (mt2 * 32 + 16 + lcol) * 40 + quad * 8);
        const f32x4 zero = {};
        const f32x4 s0 = mfma16(qa, kb0, zero);
        const f32x4 s1 = mfma16(qa, kb1, zero);
        const int nb = s * 16 + quad * 4;
#pragma unroll
        for (int t = 0; t < 2; ++t) {
          const int m = mt2 * 32 + t * 16 + lcol;
#pragma unroll
          for (int r = 0; r < 4; ++r) {
            const int n = nb + r;
            const int nc = (n < 216) ? n : 0;   // clamp for safe bias load
            float p = 0.0f;
            if (m < 216)
              p = __expf((t ? s1[r] : s0[r]) * SCALE_F + biasg[(h * 216 + nc) * 216 + m]);
            rsum[r] += p;
            pw_[(quad * 4 + r) * 40 + t * 16 + lcol] = f2bf(p);  // C-layout -> LDS
          }
        }
        __builtin_amdgcn_s_waitcnt(0);  // drain ds_writes before same-wave ds_read
        const short8 pa  = *(const short8*)(pw_ + lcol * 40 + quad * 8);          // A-layout
        const short8 vb0 = *(const short8*)(vT + lcol * 232        + mt2 * 32 + quad * 8);
        const short8 vb1 = *(const short8*)(vT + (16 + lcol) * 232 + mt2 * 32 + quad * 8);
        o0 = mfma16(pa, vb0, o0);
        o1 = mfma16(pa, vb1, o1);
      }
      // rowsum across the 16 lanes of each quad (cols partitioned by lcol)
      f32x4 inv;
#pragma unroll
      for (int r = 0; r < 4; ++r) {
        float ssum = rsum[r];
        ssum += __shfl_xor(ssum, 1, 16);
        ssum += __shfl_xor(ssum, 2, 16);
        ssum += __shfl_xor(ssum, 4, 16);
        ssum += __shfl_xor(ssum, 8, 16);
        inv[r] = 1.0f / ssum;
      }
#pragma unroll
      for (int t = 0; t < 2; ++t) {
#pragma unroll
        for (int r = 0; r < 4; ++r) {
          const int n = s * 16 + quad * 4 + r;
          if (n < 216)
            attnb[n * 192 + h * 32 + t * 16 + lcol] = f2bf((t ? o1[r] : o0[r]) * inv[r]);
        }
      }
    }
    __syncthreads();
  }
}

// ---------------------------------------------------------------------------
// K2: out = attn @ proj_w^T + proj_b, block-local in-place on d_out.
// Stage own bf16 tile -> LDS (barrier) before any fp32 write => no race.
// ---------------------------------------------------------------------------
__global__ __launch_bounds__(512, 2)
void proj_kernel(const unsigned short* __restrict__ pw, const float* __restrict__ proj_b,
                 float* __restrict__ outbuf) {
  extern __shared__ char smem[];
  unsigned short* as = (unsigned short*)smem;  // [224][200]; rows >=216 garbage (masked)
  const int b = blockIdx.x, tid = threadIdx.x;
  const int wave = tid >> 6, lane = tid & 63, quad = lane >> 4, lcol = lane & 15;
  float* myout = outbuf + (size_t)b * 41472;
  const unsigned short* attnb = (const unsigned short*)myout;

  for (int i = tid; i < 216 * 24; i += 512) {
    const int row = i / 24, c8 = i % 24;
    *(short8*)(as + row * 200 + c8 * 8) = *(const short8*)(attnb + row * 192 + c8 * 8);
  }
  __syncthreads();

  for (int u = wave; u < 14; u += 8) {   // 14 M-tiles over 8 waves
    short8 a[6];
#pragma unroll
    for (int kk = 0; kk < 6; ++kk)
      a[kk] = *(const short8*)(as + (u * 16 + lcol) * 200 + kk * 32 + quad * 8);
    for (int nt = 0; nt < 12; ++nt) {
      f32x4 acc = {};
#pragma unroll
      for (int kk = 0; kk < 6; ++kk) {
        const short8 bf = *(const short8*)(pw + (nt * 16 + lcol) * 192 + kk * 32 + quad * 8);
        acc = mfma16(a[kk], bf, acc);
      }
      const float pbv = proj_b[nt * 16 + lcol];
      const int nb = u * 16 + quad * 4;
#pragma unroll
      for (int r = 0; r < 4; ++r) {
        const int n = nb + r;
        if (n < 216) myout[n * 192 + nt * 16 + lcol] = acc[r] + pbv;
      }
    }
  }
}

// ---------------------------------------------------------------------------
extern "C" void kernel_launch(void* const* d_in, const int* in_sizes, int n_in,
                              void* d_out, int out_size, void* d_ws, size_t ws_size,
                              hipStream_t stream) {
  (void)in_sizes; (void)n_in; (void)out_size; (void)ws_size;
  const float* x          = (const float*)d_in[0];
  const float* qkv_w      = (const float*)d_in[1];
  const float* proj_w     = (const float*)d_in[2];
  const float* proj_b     = (const float*)d_in[3];
  const float* bias_table = (const float*)d_in[4];
  float* out = (float*)d_out;

  unsigned short* wb  = (unsigned short*)d_ws;                     // 221184 B
  unsigned short* pwb = (unsigned short*)((char*)d_ws + 221184);   //  73728 B
  float* biasg        = (float*)((char*)d_ws + 294912);            // 1119744 B

  (void)hipFuncSetAttribute((const void*)attn_kernel,
                            hipFuncAttributeMaxDynamicSharedMemorySize, 157568);
  (void)hipFuncSetAttribute((const void*)proj_kernel,
                            hipFuncAttributeMaxDynamicSharedMemorySize, 89600);

  prep_kernel<<<dim3(256), dim3(256), 0, stream>>>(qkv_w, proj_w, bias_table, wb, pwb, biasg);
  attn_kernel<<<dim3(1024), dim3(1024), 157568, stream>>>(x, wb, biasg, out);
  proj_kernel<<<dim3(1024), dim3(512), 89600, stream>>>(pwb, proj_b, out);
}

// Round 2
// 811.695 us; speedup vs baseline: 1.1447x; 1.1447x over previous
//
#include <hip/hip_runtime.h>
#include <cstdint>
#include <cstddef>

// ---------------------------------------------------------------------------
// WindowAttention: B=1024 windows, N=216 tokens, H=6 heads, D=32, C=192.
// K0 prep (weights->bf16, bias expand to packed bf16) ->
// K1 fused qkv+attention (bf16 MFMA, no-max softmax, hoisted bias, two-pass
// softmax/PV for ILP) -> K2 proj GEMM (LDS-staged weights) in-place on d_out.
//
// k-order permutation trick: MFMA dot products are invariant under a shared
// permutation of the K dimension. We interleave q/k d-columns (col'=2*(d&15)
// +(d>>4)) and P/vT m-columns identically, so C-layout pairs (t=0,t=1) land
// in adjacent shorts -> aligned b32 LDS writes instead of scalar b16.
// All LDS strides are 16B multiples (b128-aligned) with <=2-way banking (free).
// ---------------------------------------------------------------------------

typedef __attribute__((ext_vector_type(8))) short short8;   // 8 x bf16 frag
typedef __attribute__((ext_vector_type(4))) float f32x4;    // MFMA C/D
typedef unsigned short u16;
typedef unsigned int   u32;

#define SCALE_F 0.17677669529663687f  /* 32^-0.5 */

// LDS layout (attn): all byte offsets 16B-aligned
#define XS_OFF   0        // [224][200] u16  = 89600 (rows 216..223 uninit, masked)
#define QS_OFF   89600    // [224][40]  u16  = 17920 (rows 216..223 zeroed)
#define KS_OFF   107520   // [224][40]  u16  = 17920 (rows 216..223 zeroed)
#define VT_OFF   125440   // [32][232]  u16  = 14848 (perm cols; m-pads zeroed)
#define PCH_OFF  140288   // 14 waves x [16][40] u16 = 17920
#define ATTN_LDS 158208

#define PROJ_AS_OFF  0      // [216][200] u16 = 86400
#define PROJ_PW_OFF  86400  // [192][200] u16 = 76800
#define PROJ_LDS     163200

__device__ __forceinline__ u16 f2bf(float f) {
  union { float f; u32 u; } v; v.f = f;
  return (u16)((v.u + 0x7fffu + ((v.u >> 16) & 1u)) >> 16);  // RNE
}

__device__ __forceinline__ f32x4 mfma16(short8 a, short8 b, f32x4 c) {
  return __builtin_amdgcn_mfma_f32_16x16x32_bf16(a, b, c, 0, 0, 0);
}

// ---------------------------------------------------------------------------
// K0: qkv_w->bf16, proj_w->bf16, bias expand to [h][c][l][n:224][t:2] bf16.
// m = c*32 + t*16 + l. m>=216 -> -inf bf16 (0xFF80) so exp()->0. n>=216 -> 0.
// ---------------------------------------------------------------------------
__global__ void prep_kernel(const float* __restrict__ qkv_w,
                            const float* __restrict__ proj_w,
                            const float* __restrict__ bias_table,
                            u16* __restrict__ wb,
                            u16* __restrict__ pwb,
                            u16* __restrict__ biasp) {
  const int tid = blockIdx.x * blockDim.x + threadIdx.x;
  const int stride = gridDim.x * blockDim.x;
  for (int i = tid; i < 576 * 192; i += stride) wb[i] = f2bf(qkv_w[i]);
  for (int i = tid; i < 192 * 192; i += stride) pwb[i] = f2bf(proj_w[i]);
  for (int i = tid; i < 6 * 7 * 16 * 224 * 2; i += stride) {
    const int t = i & 1;
    int j = i >> 1;
    const int n = j % 224; j /= 224;
    const int l = j & 15;  j >>= 4;
    const int c = j % 7;
    const int h = j / 7;
    const int m = c * 32 + t * 16 + l;
    u16 val;
    if (n >= 216)      val = 0;        // pad rows: finite, discarded
    else if (m >= 216) val = 0xFF80;   // -inf bf16 -> exp = 0
    else {
      const int di = n / 36 - m / 36;
      const int dj = (n / 6) % 6 - (m / 6) % 6;
      const int dk = n % 6 - m % 6;
      const int idx = (di + 5) * 17 + (dj + 5) * 11 + (dk + 5);
      val = f2bf(bias_table[idx * 6 + h]);
    }
    biasp[i] = val;
  }
}

// ---------------------------------------------------------------------------
// K1: per-window fused qkv + attention.
// ---------------------------------------------------------------------------
__global__ __launch_bounds__(1024, 4)
void attn_kernel(const float* __restrict__ x, const u16* __restrict__ wb,
                 const u16* __restrict__ biasp, float* __restrict__ outbuf) {
  extern __shared__ char smem[];
  u16* xs  = (u16*)(smem + XS_OFF);
  u16* qs  = (u16*)(smem + QS_OFF);
  u16* ks  = (u16*)(smem + KS_OFF);
  u16* vT  = (u16*)(smem + VT_OFF);
  u16* pch = (u16*)(smem + PCH_OFF);

  const int b = blockIdx.x;
  const int tid = threadIdx.x;
  const int wave = tid >> 6;
  const int lane = tid & 63;
  const int quad = lane >> 4;
  const int lcol = lane & 15;

  // ---- stage x (fp32 -> bf16), zero the n-pad rows of qs/ks and vT m-pads ----
  {
    const float4* xg4 = (const float4*)(x + (size_t)b * 41472);
    for (int i = tid; i < 216 * 48; i += 1024) {
      const int row = i / 48, c4 = i % 48;
      const float4 v = xg4[row * 48 + c4];
      union { u16 s[4]; unsigned long long u; } pk;
      pk.s[0] = f2bf(v.x); pk.s[1] = f2bf(v.y);
      pk.s[2] = f2bf(v.z); pk.s[3] = f2bf(v.w);
      *(unsigned long long*)(xs + row * 200 + c4 * 4) = pk.u;  // 8B aligned
    }
    for (int i = tid; i < 8 * 40; i += 1024) { qs[216 * 40 + i] = 0; ks[216 * 40 + i] = 0; }
    // vT: m=216..223 -> perm cols 209,211,...,223 (odd), all 32 d-rows
    for (int i = tid; i < 32 * 8; i += 1024) {
      const int d = i >> 3, jj = i & 7;
      vT[d * 232 + 209 + 2 * jj] = 0;
    }
  }
  __syncthreads();

  u16* attnb = (u16*)(outbuf + (size_t)b * 41472);  // bf16 scratch in own out region

  for (int h = 0; h < 6; ++h) {
    // ---------- Phase 1: q,k,v = x @ W_h^T ; 14 units (one 16-row tile each) ----
    for (int u = wave; u < 14; u += 16) {
      f32x4 acc[6] = {};
#pragma unroll
      for (int kk = 0; kk < 6; ++kk) {
        const short8 a = *(const short8*)(xs + (u * 16 + lcol) * 200 + kk * 32 + quad * 8);
#pragma unroll
        for (int j = 0; j < 6; ++j) {    // 0,1=q(lo,hi) 2,3=k 4,5=v
          const int fbase = (j >> 1) * 192 + h * 32 + (j & 1) * 16;
          const short8 bf = *(const short8*)(wb + (fbase + lcol) * 192 + kk * 32 + quad * 8);
          acc[j] = mfma16(a, bf, acc[j]);
        }
      }
      const int nb = u * 16 + quad * 4;
#pragma unroll
      for (int r = 0; r < 4; ++r) {
        const int n = nb + r;
        if (n < 216) {
          // q/k: interleaved d-cols -> (j,j+1) pair = adjacent shorts = b32
          *(u32*)(qs + n * 40 + 2 * lcol) =
              (u32)f2bf(acc[0][r]) | ((u32)f2bf(acc[1][r]) << 16);
          *(u32*)(ks + n * 40 + 2 * lcol) =
              (u32)f2bf(acc[2][r]) | ((u32)f2bf(acc[3][r]) << 16);
          const int pm = (n & ~31) | (2 * (n & 15)) | ((n >> 4) & 1);  // perm m
          vT[lcol * 232 + pm]        = f2bf(acc[4][r]);
          vT[(16 + lcol) * 232 + pm] = f2bf(acc[5][r]);
        }
      }
    }
    __syncthreads();

    // ---------- Phase 2: two-pass softmax(S)+PV per 16-row strip ----------
    if (wave < 14) {
      const int s = wave;
      u16* pw_ = pch + wave * 640;  // [16][40]

      // hoisted bias: 7 x uint4, each = 4 n-rows x (t0,t1) bf16 pairs
      uint4 bias_q[7];
#pragma unroll
      for (int c = 0; c < 7; ++c)
        bias_q[c] = *(const uint4*)(biasp + ((size_t)((h * 7 + c) * 16 + lcol)) * 448
                                    + (s * 16 + quad * 4) * 2);
      const short8 qa = *(const short8*)(qs + (s * 16 + lcol) * 40 + quad * 8);

      // pass 1: S = q.k^T, p = exp(S*scale + bias) packed to bf16 in regs
      u32 pP[7][4];
      f32x4 rsum = {};
#pragma unroll
      for (int c = 0; c < 7; ++c) {
        const short8 kb0 = *(const short8*)(ks + (c * 32 + lcol) * 40 + quad * 8);
        const short8 kb1 = *(const short8*)(ks + (c * 32 + 16 + lcol) * 40 + quad * 8);
        const f32x4 z = {};
        const f32x4 s0 = mfma16(qa, kb0, z);
        const f32x4 s1 = mfma16(qa, kb1, z);
        const u32* bw = (const u32*)&bias_q[c];
#pragma unroll
        for (int r = 0; r < 4; ++r) {
          union { u32 u; float f; } b0, b1;
          b0.u = bw[r] << 16;            // t=0 bias (low short)
          b1.u = bw[r] & 0xFFFF0000u;    // t=1 bias (high short)
          const float p0 = __expf(__builtin_fmaf(s0[r], SCALE_F, b0.f));
          const float p1 = __expf(__builtin_fmaf(s1[r], SCALE_F, b1.f));
          rsum[r] += p0 + p1;
          pP[c][r] = (u32)f2bf(p0) | ((u32)f2bf(p1) << 16);  // perm col pair
        }
      }

      // pass 2: LDS C->A transform + PV (short-latency chain only)
      f32x4 o0 = {}, o1 = {};
#pragma unroll
      for (int c = 0; c < 7; ++c) {
#pragma unroll
        for (int r = 0; r < 4; ++r)
          *(u32*)(pw_ + (quad * 4 + r) * 40 + 2 * lcol) = pP[c][r];
        __builtin_amdgcn_s_waitcnt(0);   // drain writes before same-wave read
        const short8 pa  = *(const short8*)(pw_ + lcol * 40 + quad * 8);
        const short8 vb0 = *(const short8*)(vT + lcol * 232 + c * 32 + quad * 8);
        const short8 vb1 = *(const short8*)(vT + (16 + lcol) * 232 + c * 32 + quad * 8);
        o0 = mfma16(pa, vb0, o0);
        o1 = mfma16(pa, vb1, o1);
      }

      // rowsum over the 16 lcol lanes of each quad, then scale + store
      f32x4 inv;
#pragma unroll
      for (int r = 0; r < 4; ++r) {
        float ssum = rsum[r];
        ssum += __shfl_xor(ssum, 1, 16);
        ssum += __shfl_xor(ssum, 2, 16);
        ssum += __shfl_xor(ssum, 4, 16);
        ssum += __shfl_xor(ssum, 8, 16);
        inv[r] = 1.0f / ssum;
      }
#pragma unroll
      for (int r = 0; r < 4; ++r) {
        const int n = s * 16 + quad * 4 + r;
        if (n < 216) {
          attnb[n * 192 + h * 32 + lcol]      = f2bf(o0[r] * inv[r]);
          attnb[n * 192 + h * 32 + 16 + lcol] = f2bf(o1[r] * inv[r]);
        }
      }
    }
    __syncthreads();
  }
}

// ---------------------------------------------------------------------------
// K2: out = attn @ proj_w^T + proj_b, block-local in-place on d_out.
// proj_w staged in LDS (padded stride 200); A-fragments in registers.
// ---------------------------------------------------------------------------
__global__ __launch_bounds__(1024, 4)
void proj_kernel(const u16* __restrict__ pwb, const float* __restrict__ proj_b,
                 float* __restrict__ outbuf) {
  extern __shared__ char smem[];
  u16* as  = (u16*)(smem + PROJ_AS_OFF);   // [216][200]
  u16* pws = (u16*)(smem + PROJ_PW_OFF);   // [192][200]
  const int b = blockIdx.x, tid = threadIdx.x;
  const int wave = tid >> 6, lane = tid & 63, quad = lane >> 4, lcol = lane & 15;
  float* myout = outbuf + (size_t)b * 41472;
  const u16* attnb = (const u16*)myout;

  for (int i = tid; i < 216 * 24; i += 1024) {
    const int row = i / 24, c8 = i % 24;
    *(short8*)(as + row * 200 + c8 * 8) = *(const short8*)(attnb + row * 192 + c8 * 8);
  }
  for (int i = tid; i < 192 * 24; i += 1024) {
    const int row = i / 24, c8 = i % 24;
    *(short8*)(pws + row * 200 + c8 * 8) = *(const short8*)(pwb + row * 192 + c8 * 8);
  }
  __syncthreads();

  for (int u = wave; u < 14; u += 16) {
    const int arow = u * 16 + lcol;
    const bool ok = arow < 216;
    short8 a[6];
#pragma unroll
    for (int kk = 0; kk < 6; ++kk) {
      const short8 z = {};
      a[kk] = ok ? *(const short8*)(as + arow * 200 + kk * 32 + quad * 8) : z;
    }
    for (int nt = 0; nt < 12; ++nt) {
      f32x4 acc = {};
#pragma unroll
      for (int kk = 0; kk < 6; ++kk) {
        const short8 bf = *(const short8*)(pws + (nt * 16 + lcol) * 200 + kk * 32 + quad * 8);
        acc = mfma16(a[kk], bf, acc);
      }
      const float pbv = proj_b[nt * 16 + lcol];
      const int nb = u * 16 + quad * 4;
#pragma unroll
      for (int r = 0; r < 4; ++r) {
        const int n = nb + r;
        if (n < 216) myout[n * 192 + nt * 16 + lcol] = acc[r] + pbv;
      }
    }
  }
}

// ---------------------------------------------------------------------------
extern "C" void kernel_launch(void* const* d_in, const int* in_sizes, int n_in,
                              void* d_out, int out_size, void* d_ws, size_t ws_size,
                              hipStream_t stream) {
  (void)in_sizes; (void)n_in; (void)out_size; (void)ws_size;
  const float* x          = (const float*)d_in[0];
  const float* qkv_w      = (const float*)d_in[1];
  const float* proj_w     = (const float*)d_in[2];
  const float* proj_b     = (const float*)d_in[3];
  const float* bias_table = (const float*)d_in[4];
  float* out = (float*)d_out;

  u16* wb    = (u16*)d_ws;                              // 221184 B
  u16* pwb   = (u16*)((char*)d_ws + 221184);            //  73728 B
  u16* biasp = (u16*)((char*)d_ws + 294912);            // 1204224 B

  (void)hipFuncSetAttribute((const void*)attn_kernel,
                            hipFuncAttributeMaxDynamicSharedMemorySize, ATTN_LDS);
  (void)hipFuncSetAttribute((const void*)proj_kernel,
                            hipFuncAttributeMaxDynamicSharedMemorySize, PROJ_LDS);

  prep_kernel<<<dim3(512), dim3(256), 0, stream>>>(qkv_w, proj_w, bias_table, wb, pwb, biasp);
  attn_kernel<<<dim3(1024), dim3(1024), ATTN_LDS, stream>>>(x, wb, biasp, out);
  proj_kernel<<<dim3(1024), dim3(1024), PROJ_LDS, stream>>>(pwb, proj_b, out);
}